// Round 6
// baseline (3754.155 us; speedup 1.0000x reference)
//
#include <hip/hip_runtime.h>
#include <hip/hip_cooperative_groups.h>

namespace {
constexpr int T_STEPS = 16;
constexpr int BROWS   = 16;                    // batch rows
constexpr int N_ELEM  = 128 * 32 * 32;         // 131072 per sample
constexpr int K_SEL   = (N_ELEM * 50) / 100;   // 65536 : k-th largest
constexpr int BPR     = 16;                    // blocks per row
constexpr int NBLK    = BROWS * BPR;           // 256
constexpr int NTHR    = 512;
constexpr int SLICE   = N_ELEM / BPR;          // 8192 elements per block
constexpr int VITERS  = SLICE / (NTHR * 4);    // 4 float4 iters per thread
constexpr int NBINS   = 2048;
constexpr int MCAP    = 8192;                  // match-list capacity per row

// workspace layout in u32 words (total ~198K words = 775 KiB)
constexpr size_t OFF_HIST  = 0;                                  // [2][BROWS][NBINS] double-buffered
constexpr size_t SZ_HIST   = (size_t)2 * BROWS * NBINS;          // 65536
constexpr size_t OFF_MCNT  = OFF_HIST + SZ_HIST;                 // [T][BROWS]
constexpr size_t SZ_MCNT   = (size_t)T_STEPS * BROWS;            // 256
constexpr size_t OFF_FBC   = OFF_MCNT + SZ_MCNT;                 // [32][BROWS] fallback counters
constexpr size_t SZ_FBC    = (size_t)32 * BROWS;                 // 512
constexpr size_t OFF_BAR   = OFF_FBC + SZ_FBC;                   // [BROWS][64] row barrier counters (256B apart)
constexpr size_t SZ_BAR    = (size_t)BROWS * 64;                 // 1024
constexpr size_t OFF_MATCH = OFF_BAR + SZ_BAR;                   // [BROWS][MCAP]
constexpr size_t SZ_MATCH  = (size_t)BROWS * MCAP;               // 131072
constexpr size_t ZERO_WORDS = OFF_MATCH;                         // memset region
} // namespace

__device__ __forceinline__ unsigned f2k(float f) {
    unsigned u = __float_as_uint(f);
    return (u & 0x80000000u) ? ~u : (u | 0x80000000u);   // monotonic: key asc <=> value asc
}
__device__ __forceinline__ float k2f(unsigned k) {
    unsigned u = (k & 0x80000000u) ? (k & 0x7fffffffu) : ~k;
    return __uint_as_float(u);
}

// Per-row barrier among the BPR co-resident blocks of one batch row.
// Mirrors __ockl_grid_sync's fence discipline exactly:
//   release fence by EVERY thread (drains each wave's own outstanding writes)
//   -> syncthreads -> leader arrive+spin on row counter -> syncthreads
//   -> acquire fence by every thread (invalidate caches before reading peers' data).
// Monotonic counter: phase p is the p-th barrier this row has executed (1-based).
__device__ __forceinline__ void row_barrier(unsigned* bar_row, unsigned target, int tid) {
    __threadfence();                     // release: per-thread drain of global writes
    __syncthreads();
    if (tid == 0) {
        __hip_atomic_fetch_add(bar_row, 1u, __ATOMIC_RELAXED, __HIP_MEMORY_SCOPE_AGENT);
        while (__hip_atomic_load(bar_row, __ATOMIC_RELAXED, __HIP_MEMORY_SCOPE_AGENT) < target)
            __builtin_amdgcn_s_sleep(2);
    }
    __syncthreads();
    __threadfence();                     // acquire: fresh view of peers' writes
}

// Block-wide: find bin (descending key order) containing rank `rem` (1-indexed from top)
// in sh_hist[0..NBINS). Result -> sh_bcast[0]=bin, sh_bcast[1]=residual rank in bin.
__device__ void select_bin(const unsigned* sh_hist, unsigned* sh_wave,
                           unsigned* sh_bcast, unsigned rem, int tid)
{
    const int lane = tid & 63;
    const int wid  = tid >> 6;                  // 0..7
    const int b0   = NBINS - 1 - 4 * tid;       // this thread's top bin (descending chunks)
    const unsigned c0 = sh_hist[b0];
    const unsigned c1 = sh_hist[b0 - 1];
    const unsigned c2 = sh_hist[b0 - 2];
    const unsigned c3 = sh_hist[b0 - 3];
    const unsigned csum = c0 + c1 + c2 + c3;

    unsigned s = csum;                          // inclusive scan within wave
    #pragma unroll
    for (int off = 1; off < 64; off <<= 1) {
        unsigned v = __shfl_up(s, off);
        if (lane >= off) s += v;
    }
    if (lane == 63) sh_wave[wid] = s;
    __syncthreads();
    unsigned woff = 0;
    #pragma unroll
    for (int w = 0; w < 8; ++w) woff += (w < wid) ? sh_wave[w] : 0u;
    const unsigned hi = woff + s;
    const unsigned lo = hi - csum;
    if (lo < rem && rem <= hi) {                // exactly one thread
        unsigned r = rem - lo;
        int bin = b0;
        if (r > c0) { r -= c0; bin = b0 - 1;
            if (r > c1) { r -= c1; bin = b0 - 2;
                if (r > c2) { r -= c2; bin = b0 - 3; } } }
        sh_bcast[0] = (unsigned)bin;
        sh_bcast[1] = r;
    }
    __syncthreads();
}

__global__ __launch_bounds__(NTHR)
void lif_topk_coop(const float* __restrict__ x, float* __restrict__ out,
                   unsigned* __restrict__ ws)
{
    const int tid = threadIdx.x;
    const int blk = blockIdx.x;
    const int row = blk >> 4;      // batch row
    const int bir = blk & 15;      // block within row

    __shared__ float    m_lds[SLICE];       // 32 KiB membrane slice
    __shared__ unsigned sh_hist[NBINS];     // 8 KiB
    __shared__ unsigned sh_scan[NTHR];      // 2 KiB (wave sums / fallback reduce)
    __shared__ unsigned sh_bcast[2];

    unsigned* hist_all  = ws + OFF_HIST;    // [2][BROWS][NBINS]
    unsigned* mcnt_all  = ws + OFF_MCNT;    // [T][BROWS]
    unsigned* fbc       = ws + OFF_FBC;     // [32][BROWS]
    unsigned* bar_row   = ws + OFF_BAR + (size_t)row * 64;
    unsigned* match     = ws + OFF_MATCH + (size_t)row * MCAP;

    unsigned phase = 0;                     // per-row barrier phase (uniform within row)

    for (int i = tid; i < SLICE; i += NTHR) m_lds[i] = 0.0f;

    // register prefetch of x for the upcoming step
    float4 xp[VITERS];
    {
        const float* xr = x + (size_t)row * N_ELEM + (size_t)bir * SLICE;  // t = 0
        #pragma unroll
        for (int it = 0; it < VITERS; ++it)
            xp[it] = *reinterpret_cast<const float4*>(xr + it * (NTHR * 4) + tid * 4);
    }
    __syncthreads();

    for (int t = 0; t < T_STEPS; ++t) {
        unsigned* histg = hist_all + ((size_t)(t & 1) * BROWS + row) * NBINS;
        unsigned* mcnt  = mcnt_all + (size_t)t * BROWS + row;
        float*    orow  = out + ((size_t)t * BROWS + row) * N_ELEM + (size_t)bir * SLICE;

        // ---------- Phase A: leaky-integrate + per-row histogram (top 11 key bits) ----------
        for (int b = tid; b < NBINS; b += NTHR) sh_hist[b] = 0u;
        __syncthreads();
        #pragma unroll
        for (int it = 0; it < VITERS; ++it) {
            const int idx = it * (NTHR * 4) + tid * 4;
            float4 mv = *reinterpret_cast<float4*>(&m_lds[idx]);
            // 0.25*m is an exact pow2 scale -> fmaf == (0.25f*m + x) bitwise
            mv.x = fmaf(0.25f, mv.x, xp[it].x);
            mv.y = fmaf(0.25f, mv.y, xp[it].y);
            mv.z = fmaf(0.25f, mv.z, xp[it].z);
            mv.w = fmaf(0.25f, mv.w, xp[it].w);
            *reinterpret_cast<float4*>(&m_lds[idx]) = mv;
            atomicAdd(&sh_hist[f2k(mv.x) >> 21], 1u);
            atomicAdd(&sh_hist[f2k(mv.y) >> 21], 1u);
            atomicAdd(&sh_hist[f2k(mv.z) >> 21], 1u);
            atomicAdd(&sh_hist[f2k(mv.w) >> 21], 1u);
        }
        __syncthreads();
        for (int b = tid; b < NBINS; b += NTHR) {
            const unsigned v = sh_hist[b];
            if (v) atomicAdd(&histg[b], v);
        }
        row_barrier(bar_row, BPR * (++phase), tid);   // BARRIER 1: row histogram complete

        // ---------- Phase B1: locate candidate bin, gather own-slice matches ----------
        for (int b = tid; b < NBINS; b += NTHR) sh_hist[b] = histg[b];
        __syncthreads();
        select_bin(sh_hist, sh_scan, sh_bcast, (unsigned)K_SEL, tid);
        const unsigned cb   = sh_bcast[0];
        const unsigned rem2 = sh_bcast[1];
        #pragma unroll
        for (int it = 0; it < VITERS; ++it) {
            const int idx = it * (NTHR * 4) + tid * 4;
            float4 mv = *reinterpret_cast<float4*>(&m_lds[idx]);
            const unsigned kk0 = f2k(mv.x), kk1 = f2k(mv.y), kk2 = f2k(mv.z), kk3 = f2k(mv.w);
            if ((kk0 >> 21) == cb) { unsigned p = atomicAdd(mcnt, 1u); if (p < MCAP) match[p] = kk0; }
            if ((kk1 >> 21) == cb) { unsigned p = atomicAdd(mcnt, 1u); if (p < MCAP) match[p] = kk1; }
            if ((kk2 >> 21) == cb) { unsigned p = atomicAdd(mcnt, 1u); if (p < MCAP) match[p] = kk2; }
            if ((kk3 >> 21) == cb) { unsigned p = atomicAdd(mcnt, 1u); if (p < MCAP) match[p] = kk3; }
        }
        // prefetch next step's x; loads drain during the barrier + B2
        if (t + 1 < T_STEPS) {
            const float* xr = x + ((size_t)(t + 1) * BROWS + row) * N_ELEM + (size_t)bir * SLICE;
            #pragma unroll
            for (int it = 0; it < VITERS; ++it)
                xp[it] = *reinterpret_cast<const float4*>(xr + it * (NTHR * 4) + tid * 4);
        }
        row_barrier(bar_row, BPR * (++phase), tid);   // BARRIER 2: match list complete

        // ---------- Phase B2: exact threshold, spike, reset ----------
        // zero this step's global histogram buffer for reuse at t+2
        // (row peers' reads of histg all ended before BARRIER 2; next writes after BARRIER 1 of t+1)
        for (int b = tid; b < NBINS; b += NTHR) histg[b] = 0u;

        // fallback decision: per-row uniform (all row blocks read the same word)
        const unsigned rowcnt = mcnt[0];
        const bool fb = rowcnt > (unsigned)MCAP;

        unsigned thr_key;
        if (!fb) {
            const unsigned cnt = rowcnt;    // <= MCAP, == histogram count of bin cb
            // level 2: bits [20:10]
            for (int b = tid; b < NBINS; b += NTHR) sh_hist[b] = 0u;
            __syncthreads();
            for (unsigned i = tid; i < cnt; i += NTHR)
                atomicAdd(&sh_hist[(match[i] >> 10) & 0x7FFu], 1u);
            __syncthreads();
            select_bin(sh_hist, sh_scan, sh_bcast, rem2, tid);
            const unsigned cb2  = sh_bcast[0];
            const unsigned rem3 = sh_bcast[1];
            // level 3: bits [9:0]
            for (int b = tid; b < NBINS; b += NTHR) sh_hist[b] = 0u;
            __syncthreads();
            for (unsigned i = tid; i < cnt; i += NTHR) {
                const unsigned kk = match[i];
                if (((kk >> 10) & 0x7FFu) == cb2) atomicAdd(&sh_hist[kk & 0x3FFu], 1u);
            }
            __syncthreads();
            select_bin(sh_hist, sh_scan, sh_bcast, rem3, tid);
            thr_key = (cb << 21) | (cb2 << 10) | sh_bcast[0];
        } else {
            // bulletproof fallback: distributed 32-pass bitwise radix select over the
            // LDS-resident membranes. Per-row uniform branch -> phase counts stay aligned.
            unsigned prefix = 0u, remaining = (unsigned)K_SEL;
            for (int bit = 31; bit >= 0; --bit) {
                const unsigned mask = ~((1u << bit) - 1u);
                const unsigned want = prefix | (1u << bit);
                unsigned c = 0;
                for (int i = tid; i < SLICE; i += NTHR) {
                    const unsigned kk = f2k(m_lds[i]);
                    c += ((kk & mask) == want) ? 1u : 0u;
                }
                sh_scan[tid] = c; __syncthreads();
                for (int off = NTHR >> 1; off > 0; off >>= 1) {
                    if (tid < off) sh_scan[tid] += sh_scan[tid + off];
                    __syncthreads();
                }
                if (tid == 0 && sh_scan[0]) atomicAdd(&fbc[(size_t)bit * BROWS + row], sh_scan[0]);
                __syncthreads();
                row_barrier(bar_row, BPR * (++phase), tid);
                const unsigned total = fbc[(size_t)bit * BROWS + row];  // row total, uniform
                if (total >= remaining) prefix = want; else remaining -= total;
            }
            row_barrier(bar_row, BPR * (++phase), tid);  // all reads of fbc complete
            for (int b = tid; b < 32; b += NTHR) fbc[(size_t)b * BROWS + row] = 0u;  // benign dup-zero
            thr_key = prefix;
        }
        const float thr = k2f(thr_key);

        #pragma unroll
        for (int it = 0; it < VITERS; ++it) {
            const int idx = it * (NTHR * 4) + tid * 4;
            float4 mv = *reinterpret_cast<float4*>(&m_lds[idx]);
            float4 sv;
            sv.x = (mv.x >= thr) ? 1.0f : 0.0f; if (mv.x >= thr) mv.x = 0.0f;
            sv.y = (mv.y >= thr) ? 1.0f : 0.0f; if (mv.y >= thr) mv.y = 0.0f;
            sv.z = (mv.z >= thr) ? 1.0f : 0.0f; if (mv.z >= thr) mv.z = 0.0f;
            sv.w = (mv.w >= thr) ? 1.0f : 0.0f; if (mv.w >= thr) mv.w = 0.0f;
            *reinterpret_cast<float4*>(&m_lds[idx]) = mv;
            *reinterpret_cast<float4*>(orow + idx) = sv;
        }
        // no barrier needed here: BARRIER 1 of t+1 orders this B2 against t+1's B1 reads
    }
}

extern "C" void kernel_launch(void* const* d_in, const int* in_sizes, int n_in,
                              void* d_out, int out_size, void* d_ws, size_t ws_size,
                              hipStream_t stream)
{
    (void)in_sizes; (void)n_in; (void)out_size; (void)ws_size;
    const float* x  = (const float*)d_in[0];
    float*       o  = (float*)d_out;
    unsigned*    ws = (unsigned*)d_ws;

    // zero histograms + match-counts + fallback counters + barrier counters
    hipMemsetAsync(d_ws, 0, ZERO_WORDS * sizeof(unsigned), stream);

    void* args[] = { (void*)&x, (void*)&o, (void*)&ws };
    // cooperative launch solely for the all-blocks-co-resident guarantee
    // (custom spin barriers require it); grid.sync() itself is NOT used.
    hipLaunchCooperativeKernel((const void*)lif_topk_coop,
                               dim3(NBLK), dim3(NTHR), args, 0, stream);
}

// Round 7
// 2268.032 us; speedup vs baseline: 1.6552x; 1.6552x over previous
//
#include <hip/hip_runtime.h>

namespace {
constexpr int T_STEPS = 16;
constexpr int BROWS   = 16;                    // batch rows
constexpr int N_ELEM  = 128 * 32 * 32;         // 131072 per sample
constexpr int K_SEL   = (N_ELEM * 50) / 100;   // 65536 : k-th largest (median)
constexpr int NBLK    = 256;                   // 16 blocks per row
constexpr int NTHR    = 512;
constexpr int SLICE   = N_ELEM / 16;           // 8192 elements per block
constexpr int VITERS  = SLICE / (NTHR * 4);    // 4 float4 iters per thread
constexpr int NBINS   = 2048;
constexpr int MCAP    = 8192;                  // match-list capacity per row

// workspace layout in u32 words (~8.8 MB total)
constexpr size_t OFF_M     = 0;                                  // [BROWS][N_ELEM] float membrane
constexpr size_t SZ_M      = (size_t)BROWS * N_ELEM;             // 2097152
constexpr size_t OFF_HIST  = OFF_M + SZ_M;                       // [2][BROWS][NBINS] parity dbuf
constexpr size_t SZ_HIST   = (size_t)2 * BROWS * NBINS;          // 65536
constexpr size_t OFF_MCNT  = OFF_HIST + SZ_HIST;                 // [T][BROWS]
constexpr size_t SZ_MCNT   = (size_t)T_STEPS * BROWS;            // 256
constexpr size_t OFF_THR   = OFF_MCNT + SZ_MCNT;                 // [T][BROWS] float
constexpr size_t SZ_THR    = (size_t)T_STEPS * BROWS;            // 256
constexpr size_t OFF_MATCH = OFF_THR + SZ_THR;                   // [BROWS][MCAP]
} // namespace

__device__ __forceinline__ unsigned f2k(float f) {
    unsigned u = __float_as_uint(f);
    return (u & 0x80000000u) ? ~u : (u | 0x80000000u);   // monotonic: key asc <=> value asc
}
__device__ __forceinline__ float k2f(unsigned k) {
    unsigned u = (k & 0x80000000u) ? (k & 0x7fffffffu) : ~k;
    return __uint_as_float(u);
}

// Block-wide: find bin (descending key order) containing rank `rem` (1-indexed from top)
// in sh_hist[0..NBINS). Result -> sh_bcast[0]=bin, sh_bcast[1]=residual rank in bin.
// Proven correct in rounds 2/6 (absmax = 0.0).
__device__ void select_bin(const unsigned* sh_hist, unsigned* sh_wave,
                           unsigned* sh_bcast, unsigned rem, int tid)
{
    const int lane = tid & 63;
    const int wid  = tid >> 6;                  // 0..7
    const int b0   = NBINS - 1 - 4 * tid;       // this thread's top bin (descending chunks)
    const unsigned c0 = sh_hist[b0];
    const unsigned c1 = sh_hist[b0 - 1];
    const unsigned c2 = sh_hist[b0 - 2];
    const unsigned c3 = sh_hist[b0 - 3];
    const unsigned csum = c0 + c1 + c2 + c3;

    unsigned s = csum;                          // inclusive scan within wave
    #pragma unroll
    for (int off = 1; off < 64; off <<= 1) {
        unsigned v = __shfl_up(s, off);
        if (lane >= off) s += v;
    }
    if (lane == 63) sh_wave[wid] = s;
    __syncthreads();
    unsigned woff = 0;
    #pragma unroll
    for (int w = 0; w < 8; ++w) woff += (w < wid) ? sh_wave[w] : 0u;
    const unsigned hi = woff + s;
    const unsigned lo = hi - csum;
    if (lo < rem && rem <= hi) {                // exactly one thread
        unsigned r = rem - lo;
        int bin = b0;
        if (r > c0) { r -= c0; bin = b0 - 1;
            if (r > c1) { r -= c1; bin = b0 - 2;
                if (r > c2) { r -= c2; bin = b0 - 3; } } }
        sh_bcast[0] = (unsigned)bin;
        sh_bcast[1] = r;
    }
    __syncthreads();
}

// K1: spike(t-1) + reset + leaky update + per-row histogram (top 11 key bits).
__global__ __launch_bounds__(NTHR)
void k_update(const float* __restrict__ x_t, const float* __restrict__ thr_prev,
              float* __restrict__ spike_prev, float* __restrict__ m_buf,
              unsigned* __restrict__ hist_t, int t0)
{
    const int tid = threadIdx.x;
    const int row = blockIdx.x >> 4;
    const int bir = blockIdx.x & 15;
    __shared__ unsigned sh_hist[NBINS];
    for (int b = tid; b < NBINS; b += NTHR) sh_hist[b] = 0u;
    __syncthreads();

    const size_t base = (size_t)row * N_ELEM + (size_t)bir * SLICE;
    const float thr = t0 ? 0.0f : thr_prev[row];   // scalar broadcast, L2-hot

    #pragma unroll
    for (int it = 0; it < VITERS; ++it) {
        const int idx = it * (NTHR * 4) + tid * 4;
        const float4 xv = *reinterpret_cast<const float4*>(x_t + base + idx);
        float4 mv;
        if (t0) {
            mv = xv;                               // m starts at 0: m = 0.25*0 + x
        } else {
            float4 mp = *reinterpret_cast<const float4*>(m_buf + base + idx);
            float4 sv;
            sv.x = (mp.x >= thr) ? 1.0f : 0.0f;
            sv.y = (mp.y >= thr) ? 1.0f : 0.0f;
            sv.z = (mp.z >= thr) ? 1.0f : 0.0f;
            sv.w = (mp.w >= thr) ? 1.0f : 0.0f;
            *reinterpret_cast<float4*>(spike_prev + base + idx) = sv;
            mp.x = (mp.x >= thr) ? 0.0f : mp.x;    // reset fired units
            mp.y = (mp.y >= thr) ? 0.0f : mp.y;
            mp.z = (mp.z >= thr) ? 0.0f : mp.z;
            mp.w = (mp.w >= thr) ? 0.0f : mp.w;
            // 0.25*m is an exact pow2 scale -> fmaf == (0.25f*m + x) bitwise
            mv.x = fmaf(0.25f, mp.x, xv.x);
            mv.y = fmaf(0.25f, mp.y, xv.y);
            mv.z = fmaf(0.25f, mp.z, xv.z);
            mv.w = fmaf(0.25f, mp.w, xv.w);
        }
        *reinterpret_cast<float4*>(m_buf + base + idx) = mv;
        atomicAdd(&sh_hist[f2k(mv.x) >> 21], 1u);
        atomicAdd(&sh_hist[f2k(mv.y) >> 21], 1u);
        atomicAdd(&sh_hist[f2k(mv.z) >> 21], 1u);
        atomicAdd(&sh_hist[f2k(mv.w) >> 21], 1u);
    }
    __syncthreads();
    unsigned* hrow = hist_t + (size_t)row * NBINS;
    for (int b = tid; b < NBINS; b += NTHR) {
        const unsigned v = sh_hist[b];
        if (v) atomicAdd(&hrow[b], v);
    }
}

// K2: per-block redundant bin-select, gather own-slice candidate keys to global list.
__global__ __launch_bounds__(NTHR)
void k_gather(const float* __restrict__ m_buf, const unsigned* __restrict__ hist_t,
              unsigned* __restrict__ mcnt_t, unsigned* __restrict__ match_all)
{
    const int tid = threadIdx.x;
    const int row = blockIdx.x >> 4;
    const int bir = blockIdx.x & 15;
    __shared__ unsigned sh_hist[NBINS];
    __shared__ unsigned sh_wave[8];
    __shared__ unsigned sh_bcast[2];

    const unsigned* hrow = hist_t + (size_t)row * NBINS;
    for (int b = tid; b < NBINS; b += NTHR) sh_hist[b] = hrow[b];
    __syncthreads();
    select_bin(sh_hist, sh_wave, sh_bcast, (unsigned)K_SEL, tid);
    const unsigned cb = sh_bcast[0];

    unsigned* mcnt  = mcnt_t + row;
    unsigned* match = match_all + (size_t)row * MCAP;
    const size_t base = (size_t)row * N_ELEM + (size_t)bir * SLICE;
    #pragma unroll
    for (int it = 0; it < VITERS; ++it) {
        const int idx = it * (NTHR * 4) + tid * 4;
        const float4 mv = *reinterpret_cast<const float4*>(m_buf + base + idx);
        const unsigned kk0 = f2k(mv.x), kk1 = f2k(mv.y), kk2 = f2k(mv.z), kk3 = f2k(mv.w);
        if ((kk0 >> 21) == cb) { unsigned p = atomicAdd(mcnt, 1u); if (p < MCAP) match[p] = kk0; }
        if ((kk1 >> 21) == cb) { unsigned p = atomicAdd(mcnt, 1u); if (p < MCAP) match[p] = kk1; }
        if ((kk2 >> 21) == cb) { unsigned p = atomicAdd(mcnt, 1u); if (p < MCAP) match[p] = kk2; }
        if ((kk3 >> 21) == cb) { unsigned p = atomicAdd(mcnt, 1u); if (p < MCAP) match[p] = kk3; }
    }
}

// K3: one block per row. Refine bits [20:10] then [9:0] over the match list -> exact
// threshold. Also zeroes this parity's histogram row for reuse at t+2.
// Fallback (match overflow, never expected): rescan the full row from global.
__global__ __launch_bounds__(NTHR)
void k_refine(const float* __restrict__ m_buf, unsigned* __restrict__ hist_t,
              const unsigned* __restrict__ mcnt_t, const unsigned* __restrict__ match_all,
              float* __restrict__ thr_t)
{
    const int tid = threadIdx.x;
    const int row = blockIdx.x;
    __shared__ unsigned sh_hist[NBINS];
    __shared__ unsigned sh_wave[8];
    __shared__ unsigned sh_bcast[2];

    unsigned* hrow = hist_t + (size_t)row * NBINS;
    for (int b = tid; b < NBINS; b += NTHR) sh_hist[b] = hrow[b];
    __syncthreads();
    select_bin(sh_hist, sh_wave, sh_bcast, (unsigned)K_SEL, tid);
    const unsigned cb   = sh_bcast[0];
    const unsigned rem2 = sh_bcast[1];
    for (int b = tid; b < NBINS; b += NTHR) hrow[b] = 0u;   // recycle for t+2

    const unsigned cnt = mcnt_t[row];
    const unsigned* match = match_all + (size_t)row * MCAP;
    unsigned thr_key;
    if (cnt <= (unsigned)MCAP) {
        // level 2: bits [20:10]
        for (int b = tid; b < NBINS; b += NTHR) sh_hist[b] = 0u;
        __syncthreads();
        for (unsigned i = tid; i < cnt; i += NTHR)
            atomicAdd(&sh_hist[(match[i] >> 10) & 0x7FFu], 1u);
        __syncthreads();
        select_bin(sh_hist, sh_wave, sh_bcast, rem2, tid);
        const unsigned cb2  = sh_bcast[0];
        const unsigned rem3 = sh_bcast[1];
        // level 3: bits [9:0]
        for (int b = tid; b < NBINS; b += NTHR) sh_hist[b] = 0u;
        __syncthreads();
        for (unsigned i = tid; i < cnt; i += NTHR) {
            const unsigned kk = match[i];
            if (((kk >> 10) & 0x7FFu) == cb2) atomicAdd(&sh_hist[kk & 0x3FFu], 1u);
        }
        __syncthreads();
        select_bin(sh_hist, sh_wave, sh_bcast, rem3, tid);
        thr_key = (cb << 21) | (cb2 << 10) | sh_bcast[0];
    } else {
        // bulletproof fallback: rescan full row from global (L3-hot)
        const float* mrow = m_buf + (size_t)row * N_ELEM;
        for (int b = tid; b < NBINS; b += NTHR) sh_hist[b] = 0u;
        __syncthreads();
        for (int i = tid; i < N_ELEM; i += NTHR) {
            const unsigned kk = f2k(mrow[i]);
            if ((kk >> 21) == cb) atomicAdd(&sh_hist[(kk >> 10) & 0x7FFu], 1u);
        }
        __syncthreads();
        select_bin(sh_hist, sh_wave, sh_bcast, rem2, tid);
        const unsigned cb2  = sh_bcast[0];
        const unsigned rem3 = sh_bcast[1];
        for (int b = tid; b < NBINS; b += NTHR) sh_hist[b] = 0u;
        __syncthreads();
        for (int i = tid; i < N_ELEM; i += NTHR) {
            const unsigned kk = f2k(mrow[i]);
            if ((kk >> 21) == cb && ((kk >> 10) & 0x7FFu) == cb2)
                atomicAdd(&sh_hist[kk & 0x3FFu], 1u);
        }
        __syncthreads();
        select_bin(sh_hist, sh_wave, sh_bcast, rem3, tid);
        thr_key = (cb << 21) | (cb2 << 10) | sh_bcast[0];
    }
    if (tid == 0) thr_t[row] = k2f(thr_key);
}

// K4: final step's spike write (no update needed afterwards).
__global__ __launch_bounds__(NTHR)
void k_final(const float* __restrict__ m_buf, const float* __restrict__ thr_t,
             float* __restrict__ spike_out)
{
    const int tid = threadIdx.x;
    const int row = blockIdx.x >> 4;
    const int bir = blockIdx.x & 15;
    const size_t base = (size_t)row * N_ELEM + (size_t)bir * SLICE;
    const float thr = thr_t[row];
    #pragma unroll
    for (int it = 0; it < VITERS; ++it) {
        const int idx = it * (NTHR * 4) + tid * 4;
        const float4 mv = *reinterpret_cast<const float4*>(m_buf + base + idx);
        float4 sv;
        sv.x = (mv.x >= thr) ? 1.0f : 0.0f;
        sv.y = (mv.y >= thr) ? 1.0f : 0.0f;
        sv.z = (mv.z >= thr) ? 1.0f : 0.0f;
        sv.w = (mv.w >= thr) ? 1.0f : 0.0f;
        *reinterpret_cast<float4*>(spike_out + base + idx) = sv;
    }
}

extern "C" void kernel_launch(void* const* d_in, const int* in_sizes, int n_in,
                              void* d_out, int out_size, void* d_ws, size_t ws_size,
                              hipStream_t stream)
{
    (void)in_sizes; (void)n_in; (void)out_size; (void)ws_size;
    const float* x   = (const float*)d_in[0];
    float*       out = (float*)d_out;
    unsigned*    ws  = (unsigned*)d_ws;

    float*    m_buf  = (float*)d_ws;            // OFF_M = 0
    unsigned* hist   = ws + OFF_HIST;
    unsigned* mcnt   = ws + OFF_MCNT;
    float*    thr    = (float*)(ws + OFF_THR);
    unsigned* match  = ws + OFF_MATCH;

    // zero histograms + match-counts (+thr, harmless) — contiguous region
    hipMemsetAsync((char*)d_ws + OFF_HIST * sizeof(unsigned), 0,
                   (SZ_HIST + SZ_MCNT + SZ_THR) * sizeof(unsigned), stream);

    for (int t = 0; t < T_STEPS; ++t) {
        const float* x_t    = x + (size_t)t * BROWS * N_ELEM;
        unsigned*    hist_t = hist + (size_t)(t & 1) * BROWS * NBINS;
        const float* thr_p  = (t > 0) ? (thr + (size_t)(t - 1) * BROWS) : nullptr;
        float*       spk_p  = (t > 0) ? (out + (size_t)(t - 1) * BROWS * N_ELEM) : nullptr;

        k_update<<<NBLK, NTHR, 0, stream>>>(x_t, thr_p, spk_p, m_buf, hist_t, t == 0 ? 1 : 0);
        k_gather<<<NBLK, NTHR, 0, stream>>>(m_buf, hist_t, mcnt + (size_t)t * BROWS, match);
        k_refine<<<BROWS, NTHR, 0, stream>>>(m_buf, hist_t, mcnt + (size_t)t * BROWS, match,
                                             thr + (size_t)t * BROWS);
    }
    k_final<<<NBLK, NTHR, 0, stream>>>(m_buf, thr + (size_t)(T_STEPS - 1) * BROWS,
                                       out + (size_t)(T_STEPS - 1) * BROWS * N_ELEM);
}

// Round 10
// 502.755 us; speedup vs baseline: 7.4672x; 4.5112x over previous
//
#include <hip/hip_runtime.h>

namespace {
constexpr int T_STEPS = 16;
constexpr int BROWS   = 16;                    // batch rows
constexpr int N_ELEM  = 128 * 32 * 32;         // 131072 per sample
constexpr int K_SEL   = (N_ELEM * 50) / 100;   // 65536 : k-th largest (median)
constexpr int NBLK    = 256;                   // 16 blocks per row
constexpr int NTHR    = 512;
constexpr int SLICE   = N_ELEM / 16;           // 8192 elements per block
constexpr int VITERS  = SLICE / (NTHR * 4);    // 4 float4 iters per thread
constexpr int NBINS   = 2048;
constexpr int MCAP    = 8192;                  // match-list capacity per row
constexpr int LCAP    = 4096;                  // per-block LDS match staging capacity

// workspace layout in u32 words (~8.8 MB total)
constexpr size_t OFF_M     = 0;                                  // [BROWS][N_ELEM] float membrane
constexpr size_t SZ_M      = (size_t)BROWS * N_ELEM;             // 2097152
constexpr size_t OFF_HIST  = OFF_M + SZ_M;                       // [2][BROWS][NBINS] parity dbuf
constexpr size_t SZ_HIST   = (size_t)2 * BROWS * NBINS;          // 65536
constexpr size_t OFF_MCNT  = OFF_HIST + SZ_HIST;                 // [T][BROWS]
constexpr size_t SZ_MCNT   = (size_t)T_STEPS * BROWS;            // 256
constexpr size_t OFF_THR   = OFF_MCNT + SZ_MCNT;                 // [T][BROWS] float
constexpr size_t SZ_THR    = (size_t)T_STEPS * BROWS;            // 256
constexpr size_t OFF_MATCH = OFF_THR + SZ_THR;                   // [BROWS][MCAP]
} // namespace

__device__ __forceinline__ unsigned f2k(float f) {
    unsigned u = __float_as_uint(f);
    return (u & 0x80000000u) ? ~u : (u | 0x80000000u);   // monotonic: key asc <=> value asc
}
__device__ __forceinline__ float k2f(unsigned k) {
    unsigned u = (k & 0x80000000u) ? (k & 0x7fffffffu) : ~k;
    return __uint_as_float(u);
}

// Block-wide: find bin (descending key order) containing rank `rem` (1-indexed from top)
// in sh_hist[0..NBINS). Result -> sh_bcast[0]=bin, sh_bcast[1]=residual rank in bin.
// Proven correct in rounds 2/6/7 (absmax = 0.0).
__device__ void select_bin(const unsigned* sh_hist, unsigned* sh_wave,
                           unsigned* sh_bcast, unsigned rem, int tid)
{
    const int lane = tid & 63;
    const int wid  = tid >> 6;                  // 0..7
    const int b0   = NBINS - 1 - 4 * tid;       // this thread's top bin (descending chunks)
    const unsigned c0 = sh_hist[b0];
    const unsigned c1 = sh_hist[b0 - 1];
    const unsigned c2 = sh_hist[b0 - 2];
    const unsigned c3 = sh_hist[b0 - 3];
    const unsigned csum = c0 + c1 + c2 + c3;

    unsigned s = csum;                          // inclusive scan within wave
    #pragma unroll
    for (int off = 1; off < 64; off <<= 1) {
        unsigned v = __shfl_up(s, off);
        if (lane >= off) s += v;
    }
    if (lane == 63) sh_wave[wid] = s;
    __syncthreads();
    unsigned woff = 0;
    #pragma unroll
    for (int w = 0; w < 8; ++w) woff += (w < wid) ? sh_wave[w] : 0u;
    const unsigned hi = woff + s;
    const unsigned lo = hi - csum;
    if (lo < rem && rem <= hi) {                // exactly one thread
        unsigned r = rem - lo;
        int bin = b0;
        if (r > c0) { r -= c0; bin = b0 - 1;
            if (r > c1) { r -= c1; bin = b0 - 2;
                if (r > c2) { r -= c2; bin = b0 - 3; } } }
        sh_bcast[0] = (unsigned)bin;
        sh_bcast[1] = r;
    }
    __syncthreads();
}

// K1: spike(t-1) + reset + leaky update + per-row histogram (top 11 key bits).
__global__ __launch_bounds__(NTHR)
void k_update(const float* __restrict__ x_t, const float* __restrict__ thr_prev,
              float* __restrict__ spike_prev, float* __restrict__ m_buf,
              unsigned* __restrict__ hist_t, int t0)
{
    const int tid = threadIdx.x;
    const int row = blockIdx.x >> 4;
    const int bir = blockIdx.x & 15;
    __shared__ unsigned sh_hist[NBINS];
    for (int b = tid; b < NBINS; b += NTHR) sh_hist[b] = 0u;
    __syncthreads();

    const size_t base = (size_t)row * N_ELEM + (size_t)bir * SLICE;
    const float thr = t0 ? 0.0f : thr_prev[row];   // scalar broadcast, L2-hot

    #pragma unroll
    for (int it = 0; it < VITERS; ++it) {
        const int idx = it * (NTHR * 4) + tid * 4;
        const float4 xv = *reinterpret_cast<const float4*>(x_t + base + idx);
        float4 mv;
        if (t0) {
            mv = xv;                               // m starts at 0: m = 0.25*0 + x
        } else {
            float4 mp = *reinterpret_cast<const float4*>(m_buf + base + idx);
            float4 sv;
            sv.x = (mp.x >= thr) ? 1.0f : 0.0f;
            sv.y = (mp.y >= thr) ? 1.0f : 0.0f;
            sv.z = (mp.z >= thr) ? 1.0f : 0.0f;
            sv.w = (mp.w >= thr) ? 1.0f : 0.0f;
            *reinterpret_cast<float4*>(spike_prev + base + idx) = sv;
            mp.x = (mp.x >= thr) ? 0.0f : mp.x;    // reset fired units
            mp.y = (mp.y >= thr) ? 0.0f : mp.y;
            mp.z = (mp.z >= thr) ? 0.0f : mp.z;
            mp.w = (mp.w >= thr) ? 0.0f : mp.w;
            // 0.25*m is an exact pow2 scale -> fmaf == (0.25f*m + x) bitwise
            mv.x = fmaf(0.25f, mp.x, xv.x);
            mv.y = fmaf(0.25f, mp.y, xv.y);
            mv.z = fmaf(0.25f, mp.z, xv.z);
            mv.w = fmaf(0.25f, mp.w, xv.w);
        }
        *reinterpret_cast<float4*>(m_buf + base + idx) = mv;
        atomicAdd(&sh_hist[f2k(mv.x) >> 21], 1u);
        atomicAdd(&sh_hist[f2k(mv.y) >> 21], 1u);
        atomicAdd(&sh_hist[f2k(mv.z) >> 21], 1u);
        atomicAdd(&sh_hist[f2k(mv.w) >> 21], 1u);
    }
    __syncthreads();
    unsigned* hrow = hist_t + (size_t)row * NBINS;
    for (int b = tid; b < NBINS; b += NTHR) {
        const unsigned v = sh_hist[b];
        if (v) atomicAdd(&hrow[b], v);
    }
}

// K2: per-block redundant bin-select + gather own-slice candidate keys.
// v2: (a) register-prefetch the whole slice first (MLP; loads overlap hist read +
// select_bin); (b) LDS-staged compaction -> ONE global returning-atomic per block
// instead of per-match RMWs on a contended line.
__global__ __launch_bounds__(NTHR)
void k_gather(const float* __restrict__ m_buf, const unsigned* __restrict__ hist_t,
              unsigned* __restrict__ mcnt_t, unsigned* __restrict__ match_all)
{
    const int tid = threadIdx.x;
    const int row = blockIdx.x >> 4;
    const int bir = blockIdx.x & 15;
    __shared__ unsigned sh_hist[NBINS];
    __shared__ unsigned sh_wave[8];
    __shared__ unsigned sh_bcast[2];
    __shared__ unsigned sh_match[LCAP];
    __shared__ unsigned sh_lcnt;
    __shared__ unsigned sh_base;

    // 1) issue all slice loads first -> 4-deep MLP per thread, latency hidden
    const size_t base = (size_t)row * N_ELEM + (size_t)bir * SLICE;
    float4 r[VITERS];
    #pragma unroll
    for (int it = 0; it < VITERS; ++it)
        r[it] = *reinterpret_cast<const float4*>(m_buf + base + it * (NTHR * 4) + tid * 4);

    if (tid == 0) sh_lcnt = 0u;
    const unsigned* hrow = hist_t + (size_t)row * NBINS;
    for (int b = tid; b < NBINS; b += NTHR) sh_hist[b] = hrow[b];
    __syncthreads();
    select_bin(sh_hist, sh_wave, sh_bcast, (unsigned)K_SEL, tid);
    const unsigned cb = sh_bcast[0];

    // 2) compact matches into LDS (fast on-CU atomics; expected ~2-6 per block)
    #pragma unroll
    for (int it = 0; it < VITERS; ++it) {
        const unsigned kk0 = f2k(r[it].x), kk1 = f2k(r[it].y);
        const unsigned kk2 = f2k(r[it].z), kk3 = f2k(r[it].w);
        if ((kk0 >> 21) == cb) { unsigned p = atomicAdd(&sh_lcnt, 1u); if (p < LCAP) sh_match[p] = kk0; }
        if ((kk1 >> 21) == cb) { unsigned p = atomicAdd(&sh_lcnt, 1u); if (p < LCAP) sh_match[p] = kk1; }
        if ((kk2 >> 21) == cb) { unsigned p = atomicAdd(&sh_lcnt, 1u); if (p < LCAP) sh_match[p] = kk2; }
        if ((kk3 >> 21) == cb) { unsigned p = atomicAdd(&sh_lcnt, 1u); if (p < LCAP) sh_match[p] = kk3; }
    }
    __syncthreads();

    // 3) ONE global returning-atomic per block reserves a disjoint range
    const unsigned lc = sh_lcnt;
    if (lc == 0u) return;                    // uniform: lc read after barrier
    if (tid == 0) {
        // LDS overflow (never for this data): inflate count past MCAP to force the
        // row-level exact fallback in k_refine.
        const unsigned add = (lc > (unsigned)LCAP) ? lc + (unsigned)MCAP + 1u : lc;
        sh_base = atomicAdd(&mcnt_t[row], add);
    }
    __syncthreads();
    const unsigned gbase = sh_base;
    const unsigned n = (lc < (unsigned)LCAP) ? lc : (unsigned)LCAP;
    unsigned* match = match_all + (size_t)row * MCAP;
    for (unsigned i = tid; i < n; i += NTHR) {
        const unsigned p = gbase + i;
        if (p < (unsigned)MCAP) match[p] = sh_match[i];
    }
}

// K3: one block per row. Refine bits [20:10] then [9:0] over the match list -> exact
// threshold. Also zeroes this parity's histogram row for reuse at t+2.
// Fallback (match overflow, never expected): rescan the full row from global.
__global__ __launch_bounds__(NTHR)
void k_refine(const float* __restrict__ m_buf, unsigned* __restrict__ hist_t,
              const unsigned* __restrict__ mcnt_t, const unsigned* __restrict__ match_all,
              float* __restrict__ thr_t)
{
    const int tid = threadIdx.x;
    const int row = blockIdx.x;
    __shared__ unsigned sh_hist[NBINS];
    __shared__ unsigned sh_wave[8];
    __shared__ unsigned sh_bcast[2];

    unsigned* hrow = hist_t + (size_t)row * NBINS;
    for (int b = tid; b < NBINS; b += NTHR) sh_hist[b] = hrow[b];
    __syncthreads();
    select_bin(sh_hist, sh_wave, sh_bcast, (unsigned)K_SEL, tid);
    const unsigned cb   = sh_bcast[0];
    const unsigned rem2 = sh_bcast[1];
    for (int b = tid; b < NBINS; b += NTHR) hrow[b] = 0u;   // recycle for t+2

    const unsigned cnt = mcnt_t[row];
    const unsigned* match = match_all + (size_t)row * MCAP;
    unsigned thr_key;
    if (cnt <= (unsigned)MCAP) {
        // level 2: bits [20:10]
        for (int b = tid; b < NBINS; b += NTHR) sh_hist[b] = 0u;
        __syncthreads();
        for (unsigned i = tid; i < cnt; i += NTHR)
            atomicAdd(&sh_hist[(match[i] >> 10) & 0x7FFu], 1u);
        __syncthreads();
        select_bin(sh_hist, sh_wave, sh_bcast, rem2, tid);
        const unsigned cb2  = sh_bcast[0];
        const unsigned rem3 = sh_bcast[1];
        // level 3: bits [9:0]
        for (int b = tid; b < NBINS; b += NTHR) sh_hist[b] = 0u;
        __syncthreads();
        for (unsigned i = tid; i < cnt; i += NTHR) {
            const unsigned kk = match[i];
            if (((kk >> 10) & 0x7FFu) == cb2) atomicAdd(&sh_hist[kk & 0x3FFu], 1u);
        }
        __syncthreads();
        select_bin(sh_hist, sh_wave, sh_bcast, rem3, tid);
        thr_key = (cb << 21) | (cb2 << 10) | sh_bcast[0];
    } else {
        // bulletproof fallback: rescan full row from global (L3-hot)
        const float* mrow = m_buf + (size_t)row * N_ELEM;
        for (int b = tid; b < NBINS; b += NTHR) sh_hist[b] = 0u;
        __syncthreads();
        for (int i = tid; i < N_ELEM; i += NTHR) {
            const unsigned kk = f2k(mrow[i]);
            if ((kk >> 21) == cb) atomicAdd(&sh_hist[(kk >> 10) & 0x7FFu], 1u);
        }
        __syncthreads();
        select_bin(sh_hist, sh_wave, sh_bcast, rem2, tid);
        const unsigned cb2  = sh_bcast[0];
        const unsigned rem3 = sh_bcast[1];
        for (int b = tid; b < NBINS; b += NTHR) sh_hist[b] = 0u;
        __syncthreads();
        for (int i = tid; i < N_ELEM; i += NTHR) {
            const unsigned kk = f2k(mrow[i]);
            if ((kk >> 21) == cb && ((kk >> 10) & 0x7FFu) == cb2)
                atomicAdd(&sh_hist[kk & 0x3FFu], 1u);
        }
        __syncthreads();
        select_bin(sh_hist, sh_wave, sh_bcast, rem3, tid);
        thr_key = (cb << 21) | (cb2 << 10) | sh_bcast[0];
    }
    if (tid == 0) thr_t[row] = k2f(thr_key);
}

// K4: final step's spike write (no update needed afterwards).
__global__ __launch_bounds__(NTHR)
void k_final(const float* __restrict__ m_buf, const float* __restrict__ thr_t,
             float* __restrict__ spike_out)
{
    const int tid = threadIdx.x;
    const int row = blockIdx.x >> 4;
    const int bir = blockIdx.x & 15;
    const size_t base = (size_t)row * N_ELEM + (size_t)bir * SLICE;
    const float thr = thr_t[row];
    #pragma unroll
    for (int it = 0; it < VITERS; ++it) {
        const int idx = it * (NTHR * 4) + tid * 4;
        const float4 mv = *reinterpret_cast<const float4*>(m_buf + base + idx);
        float4 sv;
        sv.x = (mv.x >= thr) ? 1.0f : 0.0f;
        sv.y = (mv.y >= thr) ? 1.0f : 0.0f;
        sv.z = (mv.z >= thr) ? 1.0f : 0.0f;
        sv.w = (mv.w >= thr) ? 1.0f : 0.0f;
        *reinterpret_cast<float4*>(spike_out + base + idx) = sv;
    }
}

extern "C" void kernel_launch(void* const* d_in, const int* in_sizes, int n_in,
                              void* d_out, int out_size, void* d_ws, size_t ws_size,
                              hipStream_t stream)
{
    (void)in_sizes; (void)n_in; (void)out_size; (void)ws_size;
    const float* x   = (const float*)d_in[0];
    float*       out = (float*)d_out;
    unsigned*    ws  = (unsigned*)d_ws;

    float*    m_buf  = (float*)d_ws;            // OFF_M = 0
    unsigned* hist   = ws + OFF_HIST;
    unsigned* mcnt   = ws + OFF_MCNT;
    float*    thr    = (float*)(ws + OFF_THR);
    unsigned* match  = ws + OFF_MATCH;

    // zero histograms + match-counts (+thr, harmless) — contiguous region
    hipMemsetAsync((char*)d_ws + OFF_HIST * sizeof(unsigned), 0,
                   (SZ_HIST + SZ_MCNT + SZ_THR) * sizeof(unsigned), stream);

    for (int t = 0; t < T_STEPS; ++t) {
        const float* x_t    = x + (size_t)t * BROWS * N_ELEM;
        unsigned*    hist_t = hist + (size_t)(t & 1) * BROWS * NBINS;
        const float* thr_p  = (t > 0) ? (thr + (size_t)(t - 1) * BROWS) : nullptr;
        float*       spk_p  = (t > 0) ? (out + (size_t)(t - 1) * BROWS * N_ELEM) : nullptr;

        k_update<<<NBLK, NTHR, 0, stream>>>(x_t, thr_p, spk_p, m_buf, hist_t, t == 0 ? 1 : 0);
        k_gather<<<NBLK, NTHR, 0, stream>>>(m_buf, hist_t, mcnt + (size_t)t * BROWS, match);
        k_refine<<<BROWS, NTHR, 0, stream>>>(m_buf, hist_t, mcnt + (size_t)t * BROWS, match,
                                             thr + (size_t)t * BROWS);
    }
    k_final<<<NBLK, NTHR, 0, stream>>>(m_buf, thr + (size_t)(T_STEPS - 1) * BROWS,
                                       out + (size_t)(T_STEPS - 1) * BROWS * N_ELEM);
}